// Round 5
// baseline (1369.872 us; speedup 1.0000x reference)
//
#include <hip/hip_runtime.h>

typedef unsigned short u16;
typedef unsigned int u32;

typedef __attribute__((ext_vector_type(4))) float floatx4;
typedef __attribute__((ext_vector_type(8))) __bf16 bf16x8;

typedef __attribute__((address_space(3))) u32 lds_u32_t;
typedef __attribute__((address_space(1))) u32 glb_u32_t;

__device__ __forceinline__ void gld_lds16(const u16* g, u16* l) {
    __builtin_amdgcn_global_load_lds((glb_u32_t*)g, (lds_u32_t*)l, 16, 0, 0);
}

__device__ __forceinline__ u16 f2bf(float f) {
    u32 u = __float_as_uint(f);
    u += 0x7fffu + ((u >> 16) & 1u);
    return (u16)(u >> 16);
}
// pack two fp32 -> two bf16 (RNE) in one u32
__device__ __forceinline__ u32 pk2(float a, float b) {
    u32 x = __float_as_uint(a), y = __float_as_uint(b);
    x += 0x7fffu + ((x >> 16) & 1u);
    y += 0x7fffu + ((y >> 16) & 1u);
    return (x >> 16) | (y & 0xffff0000u);
}
// bf16 pair unpack (low/high half of a u32)
__device__ __forceinline__ float bl(u32 u) { return __uint_as_float(u << 16); }
__device__ __forceinline__ float bh(u32 u) { return __uint_as_float(u & 0xffff0000u); }

// XOR-swizzle (verified R3/R4: SQ_LDS_BANK_CONFLICT == 0, correctness passed):
// for 128B-row LDS tiles, inject row bits 0-2 (byte bits 7-9) into the 16B-slot
// index (byte bits 4-6). Involution within each 8-row stripe.
#define SWZ(d) ((d) ^ ((((d) >> 7) & 7) << 4))

#define BM 128
#define BN 128
#define BK 64   // 128B LDS rows

// elementwise f32 -> bf16, 8 elems/thread
__global__ __launch_bounds__(256) void convert_f32_bf16(
    const float* __restrict__ src, u16* __restrict__ dst)
{
    const size_t i = ((size_t)blockIdx.x * 256 + threadIdx.x) * 8;
    float4 a = *(const float4*)(src + i);
    float4 b = *(const float4*)(src + i + 4);
    *(uint4*)(dst + i) = make_uint4(pk2(a.x, a.y), pk2(a.z, a.w),
                                    pk2(b.x, b.y), pk2(b.z, b.w));
}

// XCD-chunked, bn-fastest block remap: consecutive blockIdx round-robin XCDs,
// so flat%8 = XCD. Give each XCD a contiguous wg range; within it bn varies
// fastest -> an A-tile is reused nbn times while L2-hot; XCDs fetch disjoint A.
__device__ __forceinline__ void remap_bmbn(int nbn, int& bm, int& bn) {
    const int nwg = (int)gridDim.x;             // multiple of 8 for all our grids
    const int flat = (int)blockIdx.x;
    const int wg = (flat & 7) * (nwg >> 3) + (flat >> 3);
    bn = wg % nbn;
    bm = wg / nbn;
}

// C_bf16[M,N] = A_bf16[M,K] @ Bt_bf16[N,K]^T + bias_f32[N]
// m97 structure, BK=64, swizzled LDS (stage-source + read, same involution).
__global__ __launch_bounds__(256, 2) void gemm_a16_c16(
    const u16* __restrict__ A, int lda,
    const u16* __restrict__ Bt,
    const float* __restrict__ bias,
    u16* __restrict__ C, int ldc,
    int K, int nbn)
{
    __shared__ __align__(16) u16 sA[BM * BK];   // 16 KB
    __shared__ __align__(16) u16 sB[BN * BK];   // 16 KB
    const int tid  = threadIdx.x;
    int bm, bn; remap_bmbn(nbn, bm, bn);
    const int lane = tid & 63,  wave = tid >> 6;
    const int wm   = wave >> 1, wn   = wave & 1;
    const int l15  = lane & 15, quad = lane >> 4;
    const char* sAb = (const char*)sA;
    const char* sBb = (const char*)sB;

    floatx4 acc[4][4] = {};

    for (int k0 = 0; k0 < K; k0 += BK) {
        __syncthreads();
        // stage 128x64 A and B tiles; LDS dest linear (chunk clin), global
        // source pre-swizzled by the same involution at 16B-chunk granularity
#pragma unroll
        for (int j = 0; j < 4; ++j) {
            const int clin = tid + j * 256;               // 16B chunk 0..1023
            const int csrc = clin ^ ((clin >> 3) & 7);    // chunk-level SWZ
            const int r = csrc >> 3, c = (csrc & 7) * 8;
            gld_lds16(A  + (size_t)(bm * BM + r) * lda + k0 + c, &sA[clin * 8]);
            gld_lds16(Bt + (size_t)(bn * BN + r) * K   + k0 + c, &sB[clin * 8]);
        }
        __syncthreads();

#pragma unroll
        for (int ks = 0; ks < 2; ++ks) {
            bf16x8 af[4], bfr[4];
#pragma unroll
            for (int mi = 0; mi < 4; mi++)
                af[mi] = *(const bf16x8*)(sAb +
                    SWZ((wm * 64 + mi * 16 + l15) * 128 + ks * 64 + quad * 16));
#pragma unroll
            for (int ni = 0; ni < 4; ni++)
                bfr[ni] = *(const bf16x8*)(sBb +
                    SWZ((wn * 64 + ni * 16 + l15) * 128 + ks * 64 + quad * 16));
#pragma unroll
            for (int mi = 0; mi < 4; mi++)
#pragma unroll
                for (int ni = 0; ni < 4; ni++)
                    acc[mi][ni] = __builtin_amdgcn_mfma_f32_16x16x32_bf16(
                        af[mi], bfr[ni], acc[mi][ni], 0, 0, 0);
        }
    }

    const int row0 = bm * BM + wm * 64 + quad * 4;
    const int col0 = bn * BN + wn * 64 + l15;
#pragma unroll
    for (int mi = 0; mi < 4; mi++) {
#pragma unroll
        for (int ni = 0; ni < 4; ni++) {
            const int col = col0 + ni * 16;
            const float bv = bias[col];
#pragma unroll
            for (int r = 0; r < 4; r++) {
                const int row = row0 + mi * 16 + r;
                C[(size_t)row * ldc + col] = f2bf(acc[mi][ni][r] + bv);
            }
        }
    }
}

// C_f32[M,N] = A_bf16[M,K] @ Bt_bf16[N,K]^T + bias_f32[N] + R_f32[M,N]
__global__ __launch_bounds__(256, 2) void gemm_a16_c32(
    const u16* __restrict__ A, int lda,
    const u16* __restrict__ Bt,
    const float* __restrict__ bias,
    const float* __restrict__ R, int ldr,
    float* __restrict__ C, int ldc,
    int K, int nbn)
{
    __shared__ __align__(16) u16 sA[BM * BK];
    __shared__ __align__(16) u16 sB[BN * BK];
    const int tid  = threadIdx.x;
    int bm, bn; remap_bmbn(nbn, bm, bn);
    const int lane = tid & 63,  wave = tid >> 6;
    const int wm   = wave >> 1, wn   = wave & 1;
    const int l15  = lane & 15, quad = lane >> 4;
    const char* sAb = (const char*)sA;
    const char* sBb = (const char*)sB;

    floatx4 acc[4][4] = {};

    for (int k0 = 0; k0 < K; k0 += BK) {
        __syncthreads();
#pragma unroll
        for (int j = 0; j < 4; ++j) {
            const int clin = tid + j * 256;
            const int csrc = clin ^ ((clin >> 3) & 7);
            const int r = csrc >> 3, c = (csrc & 7) * 8;
            gld_lds16(A  + (size_t)(bm * BM + r) * lda + k0 + c, &sA[clin * 8]);
            gld_lds16(Bt + (size_t)(bn * BN + r) * K   + k0 + c, &sB[clin * 8]);
        }
        __syncthreads();

#pragma unroll
        for (int ks = 0; ks < 2; ++ks) {
            bf16x8 af[4], bfr[4];
#pragma unroll
            for (int mi = 0; mi < 4; mi++)
                af[mi] = *(const bf16x8*)(sAb +
                    SWZ((wm * 64 + mi * 16 + l15) * 128 + ks * 64 + quad * 16));
#pragma unroll
            for (int ni = 0; ni < 4; ni++)
                bfr[ni] = *(const bf16x8*)(sBb +
                    SWZ((wn * 64 + ni * 16 + l15) * 128 + ks * 64 + quad * 16));
#pragma unroll
            for (int mi = 0; mi < 4; mi++)
#pragma unroll
                for (int ni = 0; ni < 4; ni++)
                    acc[mi][ni] = __builtin_amdgcn_mfma_f32_16x16x32_bf16(
                        af[mi], bfr[ni], acc[mi][ni], 0, 0, 0);
        }
    }

    const int row0 = bm * BM + wm * 64 + quad * 4;
    const int col0 = bn * BN + wn * 64 + l15;
#pragma unroll
    for (int mi = 0; mi < 4; mi++) {
#pragma unroll
        for (int ni = 0; ni < 4; ni++) {
            const int col = col0 + ni * 16;
            const float bv = bias[col];
#pragma unroll
            for (int r = 0; r < 4; r++) {
                const int row = row0 + mi * 16 + r;
                C[(size_t)row * ldc + col] =
                    acc[mi][ni][r] + bv + R[(size_t)row * ldr + col];
            }
        }
    }
}

// Per-position cross-head attention, ZERO-LDS version.
// One wave per (b,t); H=8, HD=128. lane = h*8+g.
// Scores streamed from global (same-address lanes broadcast-coalesce);
// softmax via 8-lane shfl reduce; w redistributed via shfl; PV streamed.
// Writes O in-place over Q (same-wave read-before-write only).
__global__ __launch_bounds__(256) void attn8(
    const u16* Q,
    const u16* __restrict__ KV,
    u16* O,
    int qstride, int kvstride)
{
    const int wid = threadIdx.x >> 6, lane = threadIdx.x & 63;
    const size_t pos = (size_t)blockIdx.x * 4 + wid;
    const u16* qrow  = Q  + pos * qstride;
    const u16* kvrow = KV + pos * kvstride;
    const int h = lane >> 3, g = lane & 7;

    // ---- scores: lane (h,g) computes q_h . k_g ----
    const u16* qh = qrow  + h * 128;          // 128 bf16
    const u16* kg = kvrow + g * 256;          // [k(128)|v(128)]
    float s0 = 0.f, s1 = 0.f, s2 = 0.f, s3 = 0.f;
#pragma unroll
    for (int j = 0; j < 16; ++j) {            // 16B (8 bf16) per iter
        uint4 qa = *(const uint4*)(qh + j * 8);
        uint4 ka = *(const uint4*)(kg + j * 8);
        s0 += bl(qa.x) * bl(ka.x);  s1 += bh(qa.x) * bh(ka.x);
        s2 += bl(qa.y) * bl(ka.y);  s3 += bh(qa.y) * bh(ka.y);
        s0 += bl(qa.z) * bl(ka.z);  s1 += bh(qa.z) * bh(ka.z);
        s2 += bl(qa.w) * bl(ka.w);  s3 += bh(qa.w) * bh(ka.w);
    }
    float s = ((s0 + s1) + (s2 + s3)) * 0.08838834764831845f;  // 1/sqrt(128)

    // ---- softmax over g (8 adjacent lanes share h) ----
    float m = s;
    m = fmaxf(m, __shfl_xor(m, 1, 64));
    m = fmaxf(m, __shfl_xor(m, 2, 64));
    m = fmaxf(m, __shfl_xor(m, 4, 64));
    float p = __expf(s - m);
    float sum = p;
    sum += __shfl_xor(sum, 1, 64);
    sum += __shfl_xor(sum, 2, 64);
    sum += __shfl_xor(sum, 4, 64);
    const float w = p / sum;

    // ---- PV: lane (h, db=g) owns out cols [db*16, db*16+16) of head h ----
    const int db = g;
    float o[16];
#pragma unroll
    for (int j = 0; j < 16; ++j) o[j] = 0.f;
    const u16* vbase = kvrow + 128 + db * 16;     // v_g starts at +128 in slot g
#pragma unroll
    for (int gg = 0; gg < 8; ++gg) {
        const float wv = __shfl(w, h * 8 + gg, 64);
        const u16* vp = vbase + gg * 256;
        uint4 va = *(const uint4*)(vp);
        uint4 vb = *(const uint4*)(vp + 8);
        o[0]  += wv * bl(va.x);  o[1]  += wv * bh(va.x);
        o[2]  += wv * bl(va.y);  o[3]  += wv * bh(va.y);
        o[4]  += wv * bl(va.z);  o[5]  += wv * bh(va.z);
        o[6]  += wv * bl(va.w);  o[7]  += wv * bh(va.w);
        o[8]  += wv * bl(vb.x);  o[9]  += wv * bh(vb.x);
        o[10] += wv * bl(vb.y);  o[11] += wv * bh(vb.y);
        o[12] += wv * bl(vb.z);  o[13] += wv * bh(vb.z);
        o[14] += wv * bl(vb.w);  o[15] += wv * bh(vb.w);
    }

    u16* orow = O + pos * qstride + h * 128 + db * 16;
    u32 pk[8];
#pragma unroll
    for (int j = 0; j < 8; ++j)
        pk[j] = pk2(o[2 * j], o[2 * j + 1]);
    ((uint4*)orow)[0] = make_uint4(pk[0], pk[1], pk[2], pk[3]);
    ((uint4*)orow)[1] = make_uint4(pk[4], pk[5], pk[6], pk[7]);
}

// src f32 (K,N) row-major -> dst bf16 (N,K) row-major
__global__ __launch_bounds__(256) void transpose_f32_bf16(
    const float* __restrict__ src, u16* __restrict__ dst, int K, int N)
{
    __shared__ float tile[32][33];
    const int tx = threadIdx.x & 31, ty = threadIdx.x >> 5;
    const int c0 = blockIdx.x * 32, r0 = blockIdx.y * 32;
#pragma unroll
    for (int i = 0; i < 4; i++)
        tile[ty + i * 8][tx] = src[(size_t)(r0 + ty + i * 8) * N + c0 + tx];
    __syncthreads();
#pragma unroll
    for (int i = 0; i < 4; i++)
        dst[(size_t)(c0 + ty + i * 8) * K + r0 + tx] = f2bf(tile[tx][ty + i * 8]);
}

extern "C" void kernel_launch(void* const* d_in, const int* in_sizes, int n_in,
                              void* d_out, int out_size, void* d_ws, size_t ws_size,
                              hipStream_t stream) {
    const float* liquid = (const float*)d_in[0];
    const float* mamba  = (const float*)d_in[1];
    const float* Wlq  = (const float*)d_in[2];
    const float* blq  = (const float*)d_in[3];
    const float* Wmkv = (const float*)d_in[4];
    const float* bmkv = (const float*)d_in[5];
    const float* Wmq  = (const float*)d_in[6];
    const float* bmq  = (const float*)d_in[7];
    const float* Wlkv = (const float*)d_in[8];
    const float* blkv = (const float*)d_in[9];
    const float* Wlo  = (const float*)d_in[10];
    const float* blo  = (const float*)d_in[11];
    const float* Wmo  = (const float*)d_in[12];
    const float* bmo  = (const float*)d_in[13];
    float* out = (float*)d_out;   // [enhanced_liquid | enhanced_mamba], each 32768x1024 fp32

    // workspace carve (bf16)
    u16* p = (u16*)d_ws;
    u16* WtLq  = p; p += (size_t)1024 * 1024;
    u16* WtLkv = p; p += (size_t)2048 * 1024;
    u16* WtMq  = p; p += (size_t)1024 * 1024;
    u16* WtMkv = p; p += (size_t)2048 * 1024;
    u16* WtLo  = p; p += (size_t)1024 * 1024;
    u16* WtMo  = p; p += (size_t)1024 * 1024;
    u16* Q  = p; p += (size_t)32768 * 1024;   // q_l -> a_l, then reused for q_m -> a_m
    u16* KV = p;                              // kv_m, then reused for kv_l

    // bf16 activations in second half of d_out (only written by the final GEMM,
    // strictly after their last read — stream-ordered, no race)
    u16* Lb = (u16*)(out + (size_t)32768 * 1024);          // 64 MB
    u16* Mb = Lb + (size_t)32768 * 1024;                   // 64 MB

    transpose_f32_bf16<<<dim3(32, 32), 256, 0, stream>>>(Wlq,  WtLq,  1024, 1024);
    transpose_f32_bf16<<<dim3(64, 32), 256, 0, stream>>>(Wlkv, WtLkv, 1024, 2048);
    transpose_f32_bf16<<<dim3(32, 32), 256, 0, stream>>>(Wmq,  WtMq,  1024, 1024);
    transpose_f32_bf16<<<dim3(64, 32), 256, 0, stream>>>(Wmkv, WtMkv, 1024, 2048);
    transpose_f32_bf16<<<dim3(32, 32), 256, 0, stream>>>(Wlo,  WtLo,  1024, 1024);
    transpose_f32_bf16<<<dim3(32, 32), 256, 0, stream>>>(Wmo,  WtMo,  1024, 1024);

    convert_f32_bf16<<<16384, 256, 0, stream>>>(liquid, Lb);
    convert_f32_bf16<<<16384, 256, 0, stream>>>(mamba,  Mb);

    // ---- phase L: enhanced_liquid ----
    gemm_a16_c16<<<2048, 256, 0, stream>>>(Lb, 1024, WtLq,  blq,  Q,  1024, 1024, 8);
    gemm_a16_c16<<<4096, 256, 0, stream>>>(Mb, 1024, WtMkv, bmkv, KV, 2048, 1024, 16);
    attn8<<<8192, 256, 0, stream>>>(Q, KV, Q, 1024, 2048);
    gemm_a16_c32<<<2048, 256, 0, stream>>>(Q, 1024, WtLo, blo, liquid, 1024,
                                           out, 1024, 1024, 8);

    // ---- phase M: enhanced_mamba ----
    gemm_a16_c16<<<2048, 256, 0, stream>>>(Mb, 1024, WtMq,  bmq,  Q,  1024, 1024, 8);
    gemm_a16_c16<<<4096, 256, 0, stream>>>(Lb, 1024, WtLkv, blkv, KV, 2048, 1024, 16);
    attn8<<<8192, 256, 0, stream>>>(Q, KV, Q, 1024, 2048);
    gemm_a16_c32<<<2048, 256, 0, stream>>>(Q, 1024, WtMo, bmo, mamba, 1024,
                                           out + (size_t)32768 * 1024, 1024, 1024, 8);
}

// Round 6
// 1309.125 us; speedup vs baseline: 1.0464x; 1.0464x over previous
//
#include <hip/hip_runtime.h>

typedef unsigned short u16;
typedef unsigned int u32;

typedef __attribute__((ext_vector_type(4))) float floatx4;
typedef __attribute__((ext_vector_type(8))) __bf16 bf16x8;

typedef __attribute__((address_space(3))) u32 lds_u32_t;
typedef __attribute__((address_space(1))) u32 glb_u32_t;

__device__ __forceinline__ void gld_lds16(const u16* g, u16* l) {
    __builtin_amdgcn_global_load_lds((glb_u32_t*)g, (lds_u32_t*)l, 16, 0, 0);
}

__device__ __forceinline__ u16 f2bf(float f) {
    u32 u = __float_as_uint(f);
    u += 0x7fffu + ((u >> 16) & 1u);
    return (u16)(u >> 16);
}
// pack two fp32 -> two bf16 (RNE) in one u32
__device__ __forceinline__ u32 pk2(float a, float b) {
    u32 x = __float_as_uint(a), y = __float_as_uint(b);
    x += 0x7fffu + ((x >> 16) & 1u);
    y += 0x7fffu + ((y >> 16) & 1u);
    return (x >> 16) | (y & 0xffff0000u);
}
// bf16 pair unpack (low/high half of a u32)
__device__ __forceinline__ float bl(u32 u) { return __uint_as_float(u << 16); }
__device__ __forceinline__ float bh(u32 u) { return __uint_as_float(u & 0xffff0000u); }

// XOR-swizzle (verified R3/R4/R5: SQ_LDS_BANK_CONFLICT == 0, correctness passed):
// for 128B-row LDS tiles, inject row bits 0-2 (byte bits 7-9) into the 16B-slot
// index (byte bits 4-6). Involution within each 8-row stripe.
#define SWZ(d) ((d) ^ ((((d) >> 7) & 7) << 4))

// GEMM geometry: block 256x128, 4 waves (2M x 2N), wave tile 128x64.
// LDS bytes/FLOP = (128+64)/(128*64) -> 25% less LDS-read per MFMA than 64x64.
#define BM 256
#define BN 128
#define BK 64   // 128B LDS rows

// two activations f32 -> bf16 in one launch; each half is 32768x1024 elems
__global__ __launch_bounds__(256) void convert2_f32_bf16(
    const float* __restrict__ s0, u16* __restrict__ d0,
    const float* __restrict__ s1, u16* __restrict__ d1)
{
    const size_t half = (size_t)16384 * 256 * 8;
    size_t i = ((size_t)blockIdx.x * 256 + threadIdx.x) * 8;
    const float* s = s0; u16* d = d0;
    if (i >= half) { i -= half; s = s1; d = d1; }
    float4 a = *(const float4*)(s + i);
    float4 b = *(const float4*)(s + i + 4);
    *(uint4*)(d + i) = make_uint4(pk2(a.x, a.y), pk2(a.z, a.w),
                                  pk2(b.x, b.y), pk2(b.z, b.w));
}

// XCD-chunked, bn-fastest block remap (verified R5: FETCH_SIZE 270->150MB).
__device__ __forceinline__ void remap_bmbn(int nbn, int& bm, int& bn) {
    const int nwg = (int)gridDim.x;             // multiple of 8 for all our grids
    const int flat = (int)blockIdx.x;
    const int wg = (flat & 7) * (nwg >> 3) + (flat >> 3);
    bn = wg % nbn;
    bm = wg / nbn;
}

// stage A(256x64) + B(128x64) bf16 tiles into LDS, swizzled source (R3-verified
// involution at 16B-chunk granularity; LDS dest linear for global_load_lds)
__device__ __forceinline__ void stage_tiles(
    const u16* __restrict__ A, int lda, const u16* __restrict__ Bt, int K,
    int bm, int bn, int k0, u16* sA, u16* sB, int tid)
{
#pragma unroll
    for (int j = 0; j < 8; ++j) {                     // A: 2048 chunks
        const int clin = tid + j * 256;
        const int csrc = clin ^ ((clin >> 3) & 7);
        const int r = csrc >> 3, c = (csrc & 7) * 8;
        gld_lds16(A + (size_t)(bm * BM + r) * lda + k0 + c, &sA[clin * 8]);
    }
#pragma unroll
    for (int j = 0; j < 4; ++j) {                     // B: 1024 chunks
        const int clin = tid + j * 256;
        const int csrc = clin ^ ((clin >> 3) & 7);
        const int r = csrc >> 3, c = (csrc & 7) * 8;
        gld_lds16(Bt + (size_t)(bn * BN + r) * K + k0 + c, &sB[clin * 8]);
    }
}

// C_bf16[M,N] = A_bf16[M,K] @ Bt_bf16[N,K]^T + bias_f32[N]
__global__ __launch_bounds__(256, 2) void gemm_a16_c16(
    const u16* __restrict__ A, int lda,
    const u16* __restrict__ Bt,
    const float* __restrict__ bias,
    u16* __restrict__ C, int ldc,
    int K, int nbn)
{
    __shared__ __align__(16) u16 sA[BM * BK];   // 32 KB
    __shared__ __align__(16) u16 sB[BN * BK];   // 16 KB
    const int tid  = threadIdx.x;
    int bm, bn; remap_bmbn(nbn, bm, bn);
    const int lane = tid & 63,  wave = tid >> 6;
    const int wm   = wave >> 1, wn   = wave & 1;
    const int l15  = lane & 15, quad = lane >> 4;
    const char* sAb = (const char*)sA;
    const char* sBb = (const char*)sB;

    floatx4 acc[8][4] = {};

    for (int k0 = 0; k0 < K; k0 += BK) {
        __syncthreads();
        stage_tiles(A, lda, Bt, K, bm, bn, k0, sA, sB, tid);
        __syncthreads();

#pragma unroll
        for (int ks = 0; ks < 2; ++ks) {
            bf16x8 af[8], bfr[4];
#pragma unroll
            for (int mi = 0; mi < 8; mi++)
                af[mi] = *(const bf16x8*)(sAb +
                    SWZ((wm * 128 + mi * 16 + l15) * 128 + ks * 64 + quad * 16));
#pragma unroll
            for (int ni = 0; ni < 4; ni++)
                bfr[ni] = *(const bf16x8*)(sBb +
                    SWZ((wn * 64 + ni * 16 + l15) * 128 + ks * 64 + quad * 16));
#pragma unroll
            for (int mi = 0; mi < 8; mi++)
#pragma unroll
                for (int ni = 0; ni < 4; ni++)
                    acc[mi][ni] = __builtin_amdgcn_mfma_f32_16x16x32_bf16(
                        af[mi], bfr[ni], acc[mi][ni], 0, 0, 0);
        }
    }

    const int row0 = bm * BM + wm * 128 + quad * 4;
    const int col0 = bn * BN + wn * 64 + l15;
#pragma unroll
    for (int mi = 0; mi < 8; mi++) {
#pragma unroll
        for (int ni = 0; ni < 4; ni++) {
            const int col = col0 + ni * 16;
            const float bv = bias[col];
#pragma unroll
            for (int r = 0; r < 4; r++) {
                const int row = row0 + mi * 16 + r;
                C[(size_t)row * ldc + col] = f2bf(acc[mi][ni][r] + bv);
            }
        }
    }
}

// C_f32[M,N] = A_bf16[M,K] @ Bt_bf16[N,K]^T + bias_f32[N] + R_f32[M,N]
__global__ __launch_bounds__(256, 2) void gemm_a16_c32(
    const u16* __restrict__ A, int lda,
    const u16* __restrict__ Bt,
    const float* __restrict__ bias,
    const float* __restrict__ R, int ldr,
    float* __restrict__ C, int ldc,
    int K, int nbn)
{
    __shared__ __align__(16) u16 sA[BM * BK];
    __shared__ __align__(16) u16 sB[BN * BK];
    const int tid  = threadIdx.x;
    int bm, bn; remap_bmbn(nbn, bm, bn);
    const int lane = tid & 63,  wave = tid >> 6;
    const int wm   = wave >> 1, wn   = wave & 1;
    const int l15  = lane & 15, quad = lane >> 4;
    const char* sAb = (const char*)sA;
    const char* sBb = (const char*)sB;

    floatx4 acc[8][4] = {};

    for (int k0 = 0; k0 < K; k0 += BK) {
        __syncthreads();
        stage_tiles(A, lda, Bt, K, bm, bn, k0, sA, sB, tid);
        __syncthreads();

#pragma unroll
        for (int ks = 0; ks < 2; ++ks) {
            bf16x8 af[8], bfr[4];
#pragma unroll
            for (int mi = 0; mi < 8; mi++)
                af[mi] = *(const bf16x8*)(sAb +
                    SWZ((wm * 128 + mi * 16 + l15) * 128 + ks * 64 + quad * 16));
#pragma unroll
            for (int ni = 0; ni < 4; ni++)
                bfr[ni] = *(const bf16x8*)(sBb +
                    SWZ((wn * 64 + ni * 16 + l15) * 128 + ks * 64 + quad * 16));
#pragma unroll
            for (int mi = 0; mi < 8; mi++)
#pragma unroll
                for (int ni = 0; ni < 4; ni++)
                    acc[mi][ni] = __builtin_amdgcn_mfma_f32_16x16x32_bf16(
                        af[mi], bfr[ni], acc[mi][ni], 0, 0, 0);
        }
    }

    const int row0 = bm * BM + wm * 128 + quad * 4;
    const int col0 = bn * BN + wn * 64 + l15;
#pragma unroll
    for (int mi = 0; mi < 8; mi++) {
#pragma unroll
        for (int ni = 0; ni < 4; ni++) {
            const int col = col0 + ni * 16;
            const float bv = bias[col];
#pragma unroll
            for (int r = 0; r < 4; r++) {
                const int row = row0 + mi * 16 + r;
                C[(size_t)row * ldc + col] =
                    acc[mi][ni][r] + bv + R[(size_t)row * ldr + col];
            }
        }
    }
}

// Per-position cross-head attention, ZERO-LDS version (R5).
// One wave per (b,t); H=8, HD=128. lane = h*8+g.
__global__ __launch_bounds__(256) void attn8(
    const u16* Q,
    const u16* __restrict__ KV,
    u16* O,
    int qstride, int kvstride)
{
    const int wid = threadIdx.x >> 6, lane = threadIdx.x & 63;
    const size_t pos = (size_t)blockIdx.x * 4 + wid;
    const u16* qrow  = Q  + pos * qstride;
    const u16* kvrow = KV + pos * kvstride;
    const int h = lane >> 3, g = lane & 7;

    // ---- scores: lane (h,g) computes q_h . k_g ----
    const u16* qh = qrow  + h * 128;          // 128 bf16
    const u16* kg = kvrow + g * 256;          // [k(128)|v(128)]
    float s0 = 0.f, s1 = 0.f, s2 = 0.f, s3 = 0.f;
#pragma unroll
    for (int j = 0; j < 16; ++j) {            // 16B (8 bf16) per iter
        uint4 qa = *(const uint4*)(qh + j * 8);
        uint4 ka = *(const uint4*)(kg + j * 8);
        s0 += bl(qa.x) * bl(ka.x);  s1 += bh(qa.x) * bh(ka.x);
        s2 += bl(qa.y) * bl(ka.y);  s3 += bh(qa.y) * bh(ka.y);
        s0 += bl(qa.z) * bl(ka.z);  s1 += bh(qa.z) * bh(ka.z);
        s2 += bl(qa.w) * bl(ka.w);  s3 += bh(qa.w) * bh(ka.w);
    }
    float s = ((s0 + s1) + (s2 + s3)) * 0.08838834764831845f;  // 1/sqrt(128)

    // ---- softmax over g (8 adjacent lanes share h) ----
    float m = s;
    m = fmaxf(m, __shfl_xor(m, 1, 64));
    m = fmaxf(m, __shfl_xor(m, 2, 64));
    m = fmaxf(m, __shfl_xor(m, 4, 64));
    float p = __expf(s - m);
    float sum = p;
    sum += __shfl_xor(sum, 1, 64);
    sum += __shfl_xor(sum, 2, 64);
    sum += __shfl_xor(sum, 4, 64);
    const float w = p / sum;

    // ---- PV: lane (h, db=g) owns out cols [db*16, db*16+16) of head h ----
    const int db = g;
    float o[16];
#pragma unroll
    for (int j = 0; j < 16; ++j) o[j] = 0.f;
    const u16* vbase = kvrow + 128 + db * 16;     // v_g starts at +128 in slot g
#pragma unroll
    for (int gg = 0; gg < 8; ++gg) {
        const float wv = __shfl(w, h * 8 + gg, 64);
        const u16* vp = vbase + gg * 256;
        uint4 va = *(const uint4*)(vp);
        uint4 vb = *(const uint4*)(vp + 8);
        o[0]  += wv * bl(va.x);  o[1]  += wv * bh(va.x);
        o[2]  += wv * bl(va.y);  o[3]  += wv * bh(va.y);
        o[4]  += wv * bl(va.z);  o[5]  += wv * bh(va.z);
        o[6]  += wv * bl(va.w);  o[7]  += wv * bh(va.w);
        o[8]  += wv * bl(vb.x);  o[9]  += wv * bh(vb.x);
        o[10] += wv * bl(vb.y);  o[11] += wv * bh(vb.y);
        o[12] += wv * bl(vb.z);  o[13] += wv * bh(vb.z);
        o[14] += wv * bl(vb.w);  o[15] += wv * bh(vb.w);
    }

    u16* orow = O + pos * qstride + h * 128 + db * 16;
    u32 pk[8];
#pragma unroll
    for (int j = 0; j < 8; ++j)
        pk[j] = pk2(o[2 * j], o[2 * j + 1]);
    ((uint4*)orow)[0] = make_uint4(pk[0], pk[1], pk[2], pk[3]);
    ((uint4*)orow)[1] = make_uint4(pk[4], pk[5], pk[6], pk[7]);
}

// all six weight transposes in one launch: src f32 (1024,N) -> dst bf16 (N,1024)
// blockIdx.z selects the weight; guard on blockIdx.x for N=1024 weights.
__global__ __launch_bounds__(256) void transpose6_f32_bf16(
    const float* __restrict__ s0, u16* __restrict__ d0, int n0,
    const float* __restrict__ s1, u16* __restrict__ d1, int n1,
    const float* __restrict__ s2, u16* __restrict__ d2, int n2,
    const float* __restrict__ s3, u16* __restrict__ d3, int n3,
    const float* __restrict__ s4, u16* __restrict__ d4, int n4,
    const float* __restrict__ s5, u16* __restrict__ d5, int n5)
{
    const float* srcs[6] = {s0, s1, s2, s3, s4, s5};
    u16*         dsts[6] = {d0, d1, d2, d3, d4, d5};
    const int    ns[6]   = {n0, n1, n2, n3, n4, n5};
    const int z = blockIdx.z;
    const int N = ns[z];
    const int c0 = blockIdx.x * 32;
    if (c0 >= N) return;
    const float* src = srcs[z];
    u16* dst = dsts[z];
    const int K = 1024;
    __shared__ float tile[32][33];
    const int tx = threadIdx.x & 31, ty = threadIdx.x >> 5;
    const int r0 = blockIdx.y * 32;
#pragma unroll
    for (int i = 0; i < 4; i++)
        tile[ty + i * 8][tx] = src[(size_t)(r0 + ty + i * 8) * N + c0 + tx];
    __syncthreads();
#pragma unroll
    for (int i = 0; i < 4; i++)
        dst[(size_t)(c0 + ty + i * 8) * K + r0 + tx] = f2bf(tile[tx][ty + i * 8]);
}

extern "C" void kernel_launch(void* const* d_in, const int* in_sizes, int n_in,
                              void* d_out, int out_size, void* d_ws, size_t ws_size,
                              hipStream_t stream) {
    const float* liquid = (const float*)d_in[0];
    const float* mamba  = (const float*)d_in[1];
    const float* Wlq  = (const float*)d_in[2];
    const float* blq  = (const float*)d_in[3];
    const float* Wmkv = (const float*)d_in[4];
    const float* bmkv = (const float*)d_in[5];
    const float* Wmq  = (const float*)d_in[6];
    const float* bmq  = (const float*)d_in[7];
    const float* Wlkv = (const float*)d_in[8];
    const float* blkv = (const float*)d_in[9];
    const float* Wlo  = (const float*)d_in[10];
    const float* blo  = (const float*)d_in[11];
    const float* Wmo  = (const float*)d_in[12];
    const float* bmo  = (const float*)d_in[13];
    float* out = (float*)d_out;   // [enhanced_liquid | enhanced_mamba], each 32768x1024 fp32

    // workspace carve (bf16)
    u16* p = (u16*)d_ws;
    u16* WtLq  = p; p += (size_t)1024 * 1024;
    u16* WtLkv = p; p += (size_t)2048 * 1024;
    u16* WtMq  = p; p += (size_t)1024 * 1024;
    u16* WtMkv = p; p += (size_t)2048 * 1024;
    u16* WtLo  = p; p += (size_t)1024 * 1024;
    u16* WtMo  = p; p += (size_t)1024 * 1024;
    u16* Q  = p; p += (size_t)32768 * 1024;   // q_l -> a_l, then reused for q_m -> a_m
    u16* KV = p;                              // kv_m, then reused for kv_l

    // bf16 activations in second half of d_out (only written by the final GEMM,
    // strictly after their last read — stream-ordered, no race)
    u16* Lb = (u16*)(out + (size_t)32768 * 1024);          // 64 MB
    u16* Mb = Lb + (size_t)32768 * 1024;                   // 64 MB

    transpose6_f32_bf16<<<dim3(64, 32, 6), 256, 0, stream>>>(
        Wlq,  WtLq,  1024,
        Wlkv, WtLkv, 2048,
        Wmq,  WtMq,  1024,
        Wmkv, WtMkv, 2048,
        Wlo,  WtLo,  1024,
        Wmo,  WtMo,  1024);

    convert2_f32_bf16<<<32768, 256, 0, stream>>>(liquid, Lb, mamba, Mb);

    // ---- phase L: enhanced_liquid ----
    gemm_a16_c16<<<1024, 256, 0, stream>>>(Lb, 1024, WtLq,  blq,  Q,  1024, 1024, 8);
    gemm_a16_c16<<<2048, 256, 0, stream>>>(Mb, 1024, WtMkv, bmkv, KV, 2048, 1024, 16);
    attn8<<<8192, 256, 0, stream>>>(Q, KV, Q, 1024, 2048);
    gemm_a16_c32<<<1024, 256, 0, stream>>>(Q, 1024, WtLo, blo, liquid, 1024,
                                           out, 1024, 1024, 8);

    // ---- phase M: enhanced_mamba ----
    gemm_a16_c16<<<1024, 256, 0, stream>>>(Mb, 1024, WtMq,  bmq,  Q,  1024, 1024, 8);
    gemm_a16_c16<<<2048, 256, 0, stream>>>(Lb, 1024, WtLkv, blkv, KV, 2048, 1024, 16);
    attn8<<<8192, 256, 0, stream>>>(Q, KV, Q, 1024, 2048);
    gemm_a16_c32<<<1024, 256, 0, stream>>>(Q, 1024, WtMo, bmo, mamba, 1024,
                                           out + (size_t)32768 * 1024, 1024, 1024, 8);
}